// Round 3
// baseline (4356.128 us; speedup 1.0000x reference)
//
#include <hip/hip_runtime.h>

#define NN 100000
#define NE 1600000
#define DIN 128
#define DH  128
#define DOUT 64

// Per-node slot region P: row n occupies 512 bytes at P + n*512. All fp32.
//   Layer 1: slot = agg_x[n] (128 f32, atomic target); GEMM1 overwrites the
//            full slot in place with h2[n] (128 f32).
//   Layer 2: GEMM2 overwrites bytes [0,256) with t2[n] (64 f32); then zero2
//            clears bytes [256,512) = agg2[n] (64 f32, atomic target).
// ws use: 1 MiB header (deg, dinv) + 51.2 MB slots = 52.25 MB.

// ---- degree on dst ----
__global__ __launch_bounds__(256) void k_deg(const int* __restrict__ dst, int* __restrict__ deg) {
    int e = blockIdx.x * 256 + threadIdx.x;
    if (e < NE) {
        unsigned d = (unsigned)dst[e];
        if (d < NN) atomicAdd(&deg[d], 1);
    }
}

__global__ __launch_bounds__(256) void k_dinv(const int* __restrict__ deg, float* __restrict__ dinv) {
    int n = blockIdx.x * 256 + threadIdx.x;
    if (n < NN) dinv[n] = rsqrtf(fmaxf((float)deg[n] + 1.0f, 1.0f));
}

// ---- layer-1 scatter: agg_x[d] += x[s] * dinv[s]*dinv[d]  (32 lanes/edge) ----
__global__ __launch_bounds__(256) void k_scatter1(const int* __restrict__ src,
                                                  const int* __restrict__ dst,
                                                  const float* __restrict__ dinv,
                                                  const float* __restrict__ x,
                                                  char* __restrict__ P) {
    int gid = blockIdx.x * 256 + threadIdx.x;    // NE*32 threads exactly
    int e = gid >> 5, lane = gid & 31;
    unsigned s = (unsigned)src[e], d = (unsigned)dst[e];
    if (s >= NN || d >= NN) return;
    float w = dinv[s] * dinv[d];
    float4 v = ((const float4*)(x + (size_t)s * 128))[lane];   // 32*16B = 512B row
    float* o = (float*)(P + (size_t)d * 512) + lane * 4;
    atomicAdd(o + 0, v.x * w);
    atomicAdd(o + 1, v.y * w);
    atomicAdd(o + 2, v.z * w);
    atomicAdd(o + 3, v.w * w);
}

// ---- GEMM1: h2 = relu((agg_x + x*dinv^2) @ W1 + b1), f32, in-place per slot ----
// 256 thr = 32 rows x 8 colgroups; two 64-col passes (W slice 32 KB LDS each).
__global__ __launch_bounds__(256) void k_gemm1(const float* __restrict__ x,
                                               const float* __restrict__ W1,
                                               const float* __restrict__ b1,
                                               const float* __restrict__ dinv,
                                               char* __restrict__ P) {
    __shared__ float Ws[128 * 64];   // 32 KB, [k][c] slice
    __shared__ float Xs[32 * 132];   // 16.9 KB, +4 pad
    const int tid = threadIdx.x;
    const int r0 = blockIdx.x * 32;

    for (int i = tid; i < 32 * 32; i += 256) {   // 32 rows x 32 float4-chunks
        int r = i >> 5, k4 = i & 31;
        int row = r0 + r;
        float dv = dinv[row]; float sn = dv * dv;
        float4 av = ((const float4*)(P + (size_t)row * 512))[k4];
        float4 xv = ((const float4*)(x + (size_t)row * 128))[k4];
        float4 v;
        v.x = av.x + xv.x * sn;
        v.y = av.y + xv.y * sn;
        v.z = av.z + xv.z * sn;
        v.w = av.w + xv.w * sn;
        *(float4*)&Xs[r * 132 + k4 * 4] = v;
    }

    const int r = tid >> 3, c0 = (tid & 7) * 8;
    for (int cy = 0; cy < 2; ++cy) {
        for (int i = tid; i < 128 * 64; i += 256) {
            int k = i >> 6, c = i & 63;
            Ws[i] = W1[k * 128 + cy * 64 + c];
        }
        __syncthreads();   // covers Xs staging (cy=0) and Ws slice

        float acc[8];
#pragma unroll
        for (int j = 0; j < 8; ++j) acc[j] = 0.f;
        const float* xrow = &Xs[r * 132];
#pragma unroll 4
        for (int k = 0; k < 128; ++k) {
            float xv = xrow[k];
            const float* w = &Ws[k * 64 + c0];
            float4 w0 = *(const float4*)w;
            float4 w1 = *(const float4*)(w + 4);
            acc[0] = fmaf(xv, w0.x, acc[0]);
            acc[1] = fmaf(xv, w0.y, acc[1]);
            acc[2] = fmaf(xv, w0.z, acc[2]);
            acc[3] = fmaf(xv, w0.w, acc[3]);
            acc[4] = fmaf(xv, w1.x, acc[4]);
            acc[5] = fmaf(xv, w1.y, acc[5]);
            acc[6] = fmaf(xv, w1.z, acc[6]);
            acc[7] = fmaf(xv, w1.w, acc[7]);
        }
        // epilogue: + b1, relu, f32 store in place (P reads all done pre-sync)
        float* hrow = (float*)(P + (size_t)(r0 + r) * 512) + cy * 64 + c0;
        float4 o0, o1;
        o0.x = fmaxf(acc[0] + b1[cy * 64 + c0 + 0], 0.f);
        o0.y = fmaxf(acc[1] + b1[cy * 64 + c0 + 1], 0.f);
        o0.z = fmaxf(acc[2] + b1[cy * 64 + c0 + 2], 0.f);
        o0.w = fmaxf(acc[3] + b1[cy * 64 + c0 + 3], 0.f);
        o1.x = fmaxf(acc[4] + b1[cy * 64 + c0 + 4], 0.f);
        o1.y = fmaxf(acc[5] + b1[cy * 64 + c0 + 5], 0.f);
        o1.z = fmaxf(acc[6] + b1[cy * 64 + c0 + 6], 0.f);
        o1.w = fmaxf(acc[7] + b1[cy * 64 + c0 + 7], 0.f);
        *(float4*)(hrow)     = o0;
        *(float4*)(hrow + 4) = o1;
        __syncthreads();   // before next Ws slice overwrite
    }
}

// ---- GEMM2: t2 = h2 @ W2, f32, in-place bytes [0,256) of each slot ----
__global__ __launch_bounds__(256) void k_gemm2(const float* __restrict__ W2,
                                               char* __restrict__ P) {
    __shared__ float Ws[128 * 64];   // 32 KB, [k][c]
    __shared__ float Xs[32 * 132];   // 16.9 KB
    const int tid = threadIdx.x;
    const int r0 = blockIdx.x * 32;

    for (int i = tid; i < 128 * 64; i += 256) Ws[i] = W2[i];
    for (int i = tid; i < 32 * 32; i += 256) {
        int r = i >> 5, k4 = i & 31;
        float4 hv = ((const float4*)(P + (size_t)(r0 + r) * 512))[k4];  // full 512B = h2 row
        *(float4*)&Xs[r * 132 + k4 * 4] = hv;
    }
    __syncthreads();

    const int r = tid >> 3, c0 = (tid & 7) * 8;
    float acc[8];
#pragma unroll
    for (int j = 0; j < 8; ++j) acc[j] = 0.f;
    const float* xrow = &Xs[r * 132];
#pragma unroll 4
    for (int k = 0; k < 128; ++k) {
        float xv = xrow[k];
        const float* w = &Ws[k * 64 + c0];
        float4 w0 = *(const float4*)w;
        float4 w1 = *(const float4*)(w + 4);
        acc[0] = fmaf(xv, w0.x, acc[0]);
        acc[1] = fmaf(xv, w0.y, acc[1]);
        acc[2] = fmaf(xv, w0.z, acc[2]);
        acc[3] = fmaf(xv, w0.w, acc[3]);
        acc[4] = fmaf(xv, w1.x, acc[4]);
        acc[5] = fmaf(xv, w1.y, acc[5]);
        acc[6] = fmaf(xv, w1.z, acc[6]);
        acc[7] = fmaf(xv, w1.w, acc[7]);
    }
    float* trow = (float*)(P + (size_t)(r0 + r) * 512) + c0;   // bytes [0,256)
    *(float4*)(trow)     = make_float4(acc[0], acc[1], acc[2], acc[3]);
    *(float4*)(trow + 4) = make_float4(acc[4], acc[5], acc[6], acc[7]);
}

// ---- zero agg2 stripes (bytes [256,512)) — must run AFTER gemm2 ----
__global__ __launch_bounds__(256) void k_zero2(char* __restrict__ P) {
    int id = blockIdx.x * 256 + threadIdx.x;   // NN*16 threads exactly
    int n = id >> 4, j = id & 15;
    ((float4*)(P + (size_t)n * 512 + 256))[j] = make_float4(0.f, 0.f, 0.f, 0.f);
}

// ---- layer-2 scatter: agg2[d] += t2[s] * dinv[s]*dinv[d]  (16 lanes/edge) ----
__global__ __launch_bounds__(256) void k_scatter2(const int* __restrict__ src,
                                                  const int* __restrict__ dst,
                                                  const float* __restrict__ dinv,
                                                  char* __restrict__ P) {
    int gid = blockIdx.x * 256 + threadIdx.x;    // NE*16 threads exactly
    int e = gid >> 4, lane = gid & 15;
    unsigned s = (unsigned)src[e], d = (unsigned)dst[e];
    if (s >= NN || d >= NN) return;
    float w = dinv[s] * dinv[d];
    float4 v = ((const float4*)(P + (size_t)s * 512))[lane];   // t2: bytes [0,256)
    float* o = (float*)(P + (size_t)d * 512 + 256) + lane * 4;
    atomicAdd(o + 0, v.x * w);
    atomicAdd(o + 1, v.y * w);
    atomicAdd(o + 2, v.z * w);
    atomicAdd(o + 3, v.w * w);
}

// ---- out = agg2 + t2*dinv^2 + b2 (fp32 out) ----
__global__ __launch_bounds__(256) void k_out(const char* __restrict__ P,
                                             const float* __restrict__ dinv,
                                             const float* __restrict__ b2,
                                             float* __restrict__ outp) {
    int id = blockIdx.x * 256 + threadIdx.x;   // NN*16 threads exactly
    int n = id >> 4, j = id & 15;
    float dv = dinv[n]; float sn = dv * dv;
    float4 a = ((const float4*)(P + (size_t)n * 512 + 256))[j];
    float4 t = ((const float4*)(P + (size_t)n * 512))[j];
    int c = j * 4;
    float4 o;
    o.x = a.x + t.x * sn + b2[c + 0];
    o.y = a.y + t.y * sn + b2[c + 1];
    o.z = a.z + t.z * sn + b2[c + 2];
    o.w = a.w + t.w * sn + b2[c + 3];
    ((float4*)outp)[id] = o;
}

extern "C" void kernel_launch(void* const* d_in, const int* in_sizes, int n_in,
                              void* d_out, int out_size, void* d_ws, size_t ws_size,
                              hipStream_t stream) {
    const float* x  = (const float*)d_in[0];
    const int*   ei = (const int*)d_in[1];
    const float* W1 = (const float*)d_in[2];
    const float* b1 = (const float*)d_in[3];
    const float* W2 = (const float*)d_in[4];
    const float* b2 = (const float*)d_in[5];
    float* out = (float*)d_out;
    const int* src = ei;
    const int* dst = ei + NE;

    char* ws   = (char*)d_ws;
    int*   deg  = (int*)(ws + 0);            // 400,000 B
    float* dinv = (float*)(ws + 400000);     // 400,000 B
    char*  P    = ws + (1u << 20);           // NN*512 = 51,200,000 B

    hipMemsetAsync(deg, 0, (size_t)NN * 4, stream);
    hipMemsetAsync(P, 0, (size_t)NN * 512, stream);   // zero agg_x

    k_deg<<<NE / 256, 256, 0, stream>>>(dst, deg);
    k_dinv<<<(NN + 255) / 256, 256, 0, stream>>>(deg, dinv);

    k_scatter1<<<NE * 32 / 256, 256, 0, stream>>>(src, dst, dinv, x, P);
    k_gemm1<<<NN / 32, 256, 0, stream>>>(x, W1, b1, dinv, P);

    k_gemm2<<<NN / 32, 256, 0, stream>>>(W2, P);
    k_zero2<<<NN * 16 / 256, 256, 0, stream>>>(P);
    k_scatter2<<<NE * 16 / 256, 256, 0, stream>>>(src, dst, dinv, P);
    k_out<<<NN * 16 / 256, 256, 0, stream>>>(P, dinv, b2, out);
}

// Round 4
// 587.872 us; speedup vs baseline: 7.4100x; 7.4100x over previous
//
#include <hip/hip_runtime.h>

#define NN 100000
#define NE 1600000
#define DIN 128
#define DH  128
#define DOUT 64
#define NB_SCAN 391   // ceil(NN/256)

// ws layout (bytes), all 16-aligned:
//   deg:       0         (400,000)
//   dinv:      400,000   (400,000)
//   row_start: 800,016   ((NN+1)*4)
//   cursor:    1,200,032 (400,000)
//   part:      1,600,048 (NB_SCAN*4)
//   csr_src:   2,000,000 (NE*4 = 6.4 MB)
//   csr_w:     8,400,000 (NE*4 = 6.4 MB)
//   P:         16,777,216 (NN*512 = 51.2 MB)   total ~64.9 MB
// P slot per node (512 B): agg_x(128f) -> h2(128f) in place -> t2(64f) in bytes [0,256).

// ---- degree on dst ----
__global__ __launch_bounds__(256) void k_deg(const int* __restrict__ dst, int* __restrict__ deg) {
    int e = blockIdx.x * 256 + threadIdx.x;
    if (e < NE) {
        unsigned d = (unsigned)dst[e];
        if (d < NN) atomicAdd(&deg[d], 1);
    }
}

__global__ __launch_bounds__(256) void k_dinv(const int* __restrict__ deg, float* __restrict__ dinv) {
    int n = blockIdx.x * 256 + threadIdx.x;
    if (n < NN) dinv[n] = rsqrtf(fmaxf((float)deg[n] + 1.0f, 1.0f));
}

// ---- scan step 1: per-block exclusive scan of deg, block totals to part ----
__global__ __launch_bounds__(256) void k_scan1(const int* __restrict__ deg,
                                               int* __restrict__ row_start,
                                               int* __restrict__ part) {
    __shared__ int s[256];
    int tid = threadIdx.x;
    int i = blockIdx.x * 256 + tid;
    int v = (i < NN) ? deg[i] : 0;
    s[tid] = v;
    __syncthreads();
    for (int off = 1; off < 256; off <<= 1) {
        int t = (tid >= off) ? s[tid - off] : 0;
        __syncthreads();
        s[tid] += t;
        __syncthreads();
    }
    if (i < NN) row_start[i] = s[tid] - v;     // exclusive
    if (tid == 255) part[blockIdx.x] = s[255]; // block total
}

// ---- scan step 2: exclusive scan of block totals (1 block) ----
__global__ __launch_bounds__(512) void k_scan2(int* __restrict__ part) {
    __shared__ int s[512];
    int tid = threadIdx.x;
    int v = (tid < NB_SCAN) ? part[tid] : 0;
    s[tid] = v;
    __syncthreads();
    for (int off = 1; off < 512; off <<= 1) {
        int t = (tid >= off) ? s[tid - off] : 0;
        __syncthreads();
        s[tid] += t;
        __syncthreads();
    }
    if (tid < NB_SCAN) part[tid] = s[tid] - v;
}

// ---- scan step 3: add block offsets; init cursor; cap row_start[NN] ----
__global__ __launch_bounds__(256) void k_scan3(int* __restrict__ row_start,
                                               const int* __restrict__ part,
                                               int* __restrict__ cursor) {
    int i = blockIdx.x * 256 + threadIdx.x;
    if (i < NN) {
        int rs = row_start[i] + part[blockIdx.x];
        row_start[i] = rs;
        cursor[i] = rs;
    }
    if (i == 0) row_start[NN] = NE;
}

// ---- CSR fill: bucket edges by dst ----
__global__ __launch_bounds__(256) void k_fill(const int* __restrict__ src,
                                              const int* __restrict__ dst,
                                              const float* __restrict__ dinv,
                                              int* __restrict__ cursor,
                                              int* __restrict__ csr_src,
                                              float* __restrict__ csr_w) {
    int e = blockIdx.x * 256 + threadIdx.x;
    if (e >= NE) return;
    unsigned s = (unsigned)src[e], d = (unsigned)dst[e];
    if (s >= NN || d >= NN) return;
    int pos = atomicAdd(&cursor[d], 1);
    csr_src[pos] = (int)s;
    csr_w[pos] = dinv[s] * dinv[d];
}

// ---- layer-1 aggregate (gather): P[n] = x[n]*dinv^2 + sum_e w_e * x[src_e] ----
// one wave per node; lane holds float2 (128 floats / 64 lanes)
__global__ __launch_bounds__(256) void k_agg1(const float* __restrict__ x,
                                              const float* __restrict__ dinv,
                                              const int* __restrict__ row_start,
                                              const int* __restrict__ csr_src,
                                              const float* __restrict__ csr_w,
                                              char* __restrict__ P) {
    int node = blockIdx.x * 4 + (threadIdx.x >> 6);   // grid = NN/4 exactly
    int lane = threadIdx.x & 63;
    float dv = dinv[node]; float sn = dv * dv;
    float2 acc = ((const float2*)(x + (size_t)node * 128))[lane];
    acc.x *= sn; acc.y *= sn;                          // self-loop term
    int base = row_start[node], end = row_start[node + 1];
    for (int i0 = base; i0 < end; i0 += 64) {
        int idx = i0 + lane;
        int sj = 0; float wj = 0.f;
        if (idx < end) { sj = csr_src[idx]; wj = csr_w[idx]; }
        int m = min(64, end - i0);
        int j = 0;
        for (; j + 1 < m; j += 2) {
            int   s0 = __shfl(sj, j),     s1 = __shfl(sj, j + 1);
            float w0 = __shfl(wj, j),     w1 = __shfl(wj, j + 1);
            float2 v0 = ((const float2*)(x + (size_t)s0 * 128))[lane];
            float2 v1 = ((const float2*)(x + (size_t)s1 * 128))[lane];
            acc.x = fmaf(v0.x, w0, acc.x); acc.y = fmaf(v0.y, w0, acc.y);
            acc.x = fmaf(v1.x, w1, acc.x); acc.y = fmaf(v1.y, w1, acc.y);
        }
        if (j < m) {
            int s0 = __shfl(sj, j); float w0 = __shfl(wj, j);
            float2 v0 = ((const float2*)(x + (size_t)s0 * 128))[lane];
            acc.x = fmaf(v0.x, w0, acc.x); acc.y = fmaf(v0.y, w0, acc.y);
        }
    }
    ((float2*)(P + (size_t)node * 512))[lane] = acc;
}

// ---- GEMM1: h2 = relu(P @ W1 + b1), f32, in-place per slot ----
__global__ __launch_bounds__(256) void k_gemm1(const float* __restrict__ W1,
                                               const float* __restrict__ b1,
                                               char* __restrict__ P) {
    __shared__ float Ws[128 * 64];   // 32 KB slice
    __shared__ float Xs[32 * 132];
    const int tid = threadIdx.x;
    const int r0 = blockIdx.x * 32;

    for (int i = tid; i < 32 * 32; i += 256) {
        int r = i >> 5, k4 = i & 31;
        float4 av = ((const float4*)(P + (size_t)(r0 + r) * 512))[k4];
        *(float4*)&Xs[r * 132 + k4 * 4] = av;
    }

    const int r = tid >> 3, c0 = (tid & 7) * 8;
    for (int cy = 0; cy < 2; ++cy) {
        for (int i = tid; i < 128 * 64; i += 256) {
            int k = i >> 6, c = i & 63;
            Ws[i] = W1[k * 128 + cy * 64 + c];
        }
        __syncthreads();

        float acc[8];
#pragma unroll
        for (int j = 0; j < 8; ++j) acc[j] = 0.f;
        const float* xrow = &Xs[r * 132];
#pragma unroll 4
        for (int k = 0; k < 128; ++k) {
            float xv = xrow[k];
            const float* w = &Ws[k * 64 + c0];
            float4 w0 = *(const float4*)w;
            float4 w1 = *(const float4*)(w + 4);
            acc[0] = fmaf(xv, w0.x, acc[0]);
            acc[1] = fmaf(xv, w0.y, acc[1]);
            acc[2] = fmaf(xv, w0.z, acc[2]);
            acc[3] = fmaf(xv, w0.w, acc[3]);
            acc[4] = fmaf(xv, w1.x, acc[4]);
            acc[5] = fmaf(xv, w1.y, acc[5]);
            acc[6] = fmaf(xv, w1.z, acc[6]);
            acc[7] = fmaf(xv, w1.w, acc[7]);
        }
        float* hrow = (float*)(P + (size_t)(r0 + r) * 512) + cy * 64 + c0;
        float4 o0, o1;
        o0.x = fmaxf(acc[0] + b1[cy * 64 + c0 + 0], 0.f);
        o0.y = fmaxf(acc[1] + b1[cy * 64 + c0 + 1], 0.f);
        o0.z = fmaxf(acc[2] + b1[cy * 64 + c0 + 2], 0.f);
        o0.w = fmaxf(acc[3] + b1[cy * 64 + c0 + 3], 0.f);
        o1.x = fmaxf(acc[4] + b1[cy * 64 + c0 + 4], 0.f);
        o1.y = fmaxf(acc[5] + b1[cy * 64 + c0 + 5], 0.f);
        o1.z = fmaxf(acc[6] + b1[cy * 64 + c0 + 6], 0.f);
        o1.w = fmaxf(acc[7] + b1[cy * 64 + c0 + 7], 0.f);
        *(float4*)(hrow)     = o0;
        *(float4*)(hrow + 4) = o1;
        __syncthreads();
    }
}

// ---- GEMM2: t2 = h2 @ W2, f32, in-place bytes [0,256) of each slot ----
__global__ __launch_bounds__(256) void k_gemm2(const float* __restrict__ W2,
                                               char* __restrict__ P) {
    __shared__ float Ws[128 * 64];
    __shared__ float Xs[32 * 132];
    const int tid = threadIdx.x;
    const int r0 = blockIdx.x * 32;

    for (int i = tid; i < 128 * 64; i += 256) Ws[i] = W2[i];
    for (int i = tid; i < 32 * 32; i += 256) {
        int r = i >> 5, k4 = i & 31;
        float4 hv = ((const float4*)(P + (size_t)(r0 + r) * 512))[k4];
        *(float4*)&Xs[r * 132 + k4 * 4] = hv;
    }
    __syncthreads();

    const int r = tid >> 3, c0 = (tid & 7) * 8;
    float acc[8];
#pragma unroll
    for (int j = 0; j < 8; ++j) acc[j] = 0.f;
    const float* xrow = &Xs[r * 132];
#pragma unroll 4
    for (int k = 0; k < 128; ++k) {
        float xv = xrow[k];
        const float* w = &Ws[k * 64 + c0];
        float4 w0 = *(const float4*)w;
        float4 w1 = *(const float4*)(w + 4);
        acc[0] = fmaf(xv, w0.x, acc[0]);
        acc[1] = fmaf(xv, w0.y, acc[1]);
        acc[2] = fmaf(xv, w0.z, acc[2]);
        acc[3] = fmaf(xv, w0.w, acc[3]);
        acc[4] = fmaf(xv, w1.x, acc[4]);
        acc[5] = fmaf(xv, w1.y, acc[5]);
        acc[6] = fmaf(xv, w1.z, acc[6]);
        acc[7] = fmaf(xv, w1.w, acc[7]);
    }
    float* trow = (float*)(P + (size_t)(r0 + r) * 512) + c0;
    *(float4*)(trow)     = make_float4(acc[0], acc[1], acc[2], acc[3]);
    *(float4*)(trow + 4) = make_float4(acc[4], acc[5], acc[6], acc[7]);
}

// ---- layer-2 aggregate + epilogue fused: out[n] = t2[n]*sn + sum w_e*t2[src] + b2 ----
// one wave per node; lane holds 1 float (64 floats)
__global__ __launch_bounds__(256) void k_agg2(const float* __restrict__ dinv,
                                              const int* __restrict__ row_start,
                                              const int* __restrict__ csr_src,
                                              const float* __restrict__ csr_w,
                                              const char* __restrict__ P,
                                              const float* __restrict__ b2,
                                              float* __restrict__ outp) {
    int node = blockIdx.x * 4 + (threadIdx.x >> 6);   // grid = NN/4 exactly
    int lane = threadIdx.x & 63;
    float dv = dinv[node]; float sn = dv * dv;
    float acc = ((const float*)(P + (size_t)node * 512))[lane] * sn;
    int base = row_start[node], end = row_start[node + 1];
    for (int i0 = base; i0 < end; i0 += 64) {
        int idx = i0 + lane;
        int sj = 0; float wj = 0.f;
        if (idx < end) { sj = csr_src[idx]; wj = csr_w[idx]; }
        int m = min(64, end - i0);
        int j = 0;
        for (; j + 1 < m; j += 2) {
            int   s0 = __shfl(sj, j),  s1 = __shfl(sj, j + 1);
            float w0 = __shfl(wj, j),  w1 = __shfl(wj, j + 1);
            float v0 = ((const float*)(P + (size_t)s0 * 512))[lane];
            float v1 = ((const float*)(P + (size_t)s1 * 512))[lane];
            acc = fmaf(v0, w0, acc);
            acc = fmaf(v1, w1, acc);
        }
        if (j < m) {
            int s0 = __shfl(sj, j); float w0 = __shfl(wj, j);
            float v0 = ((const float*)(P + (size_t)s0 * 512))[lane];
            acc = fmaf(v0, w0, acc);
        }
    }
    outp[(size_t)node * 64 + lane] = acc + b2[lane];
}

extern "C" void kernel_launch(void* const* d_in, const int* in_sizes, int n_in,
                              void* d_out, int out_size, void* d_ws, size_t ws_size,
                              hipStream_t stream) {
    const float* x  = (const float*)d_in[0];
    const int*   ei = (const int*)d_in[1];
    const float* W1 = (const float*)d_in[2];
    const float* b1 = (const float*)d_in[3];
    const float* W2 = (const float*)d_in[4];
    const float* b2 = (const float*)d_in[5];
    float* out = (float*)d_out;
    const int* src = ei;
    const int* dst = ei + NE;

    char* ws = (char*)d_ws;
    int*   deg       = (int*)(ws + 0);
    float* dinv      = (float*)(ws + 400000);
    int*   row_start = (int*)(ws + 800016);
    int*   cursor    = (int*)(ws + 1200032);
    int*   part      = (int*)(ws + 1600048);
    int*   csr_src   = (int*)(ws + 2000000);
    float* csr_w     = (float*)(ws + 8400000);
    char*  P         = ws + 16777216;

    hipMemsetAsync(deg, 0, (size_t)NN * 4, stream);

    k_deg  <<<NE / 256, 256, 0, stream>>>(dst, deg);
    k_dinv <<<NB_SCAN, 256, 0, stream>>>(deg, dinv);
    k_scan1<<<NB_SCAN, 256, 0, stream>>>(deg, row_start, part);
    k_scan2<<<1, 512, 0, stream>>>(part);
    k_scan3<<<NB_SCAN, 256, 0, stream>>>(row_start, part, cursor);
    k_fill <<<NE / 256, 256, 0, stream>>>(src, dst, dinv, cursor, csr_src, csr_w);

    k_agg1 <<<NN / 4, 256, 0, stream>>>(x, dinv, row_start, csr_src, csr_w, P);
    k_gemm1<<<NN / 32, 256, 0, stream>>>(W1, b1, P);
    k_gemm2<<<NN / 32, 256, 0, stream>>>(W2, P);
    k_agg2 <<<NN / 4, 256, 0, stream>>>(dinv, row_start, csr_src, csr_w, P, b2, out);
}

// Round 5
// 464.593 us; speedup vs baseline: 9.3762x; 1.2653x over previous
//
#include <hip/hip_runtime.h>

#define NN 100000
#define NE 1600000
#define DIN 128
#define DH  128
#define DOUT 64
#define NB_SCAN 391   // ceil(NN/256)
#define NBG 1563      // ceil(NN/64) for MFMA gemms

// ws layout (bytes):
//   deg:       0          (400,000)
//   dinv:      400,000    (400,000)
//   row_start: 800,000    ((NN+1)*4)
//   cursor:    1,200,016  (400,000)
//   part:      1,600,016  (~1,600)
//   xb:        1,601,600  (NN*128*2 = 25.6 MB)
//   csr:       27,201,600 (NE*8 = 12.8 MB, int2{src, w-bits})
//   P:         40,001,600 (NN*512 = 51.2 MB)      total ~91.2 MB
// P slot (512 B): agg_x bf16 [0,256) -> gemm1 writes h2 bf16 [256,512)
//                 -> gemm2 writes t2 bf16 [0,128) -> agg2 gathers [0,128).

typedef short bf16x8 __attribute__((ext_vector_type(8)));
typedef float f32x4  __attribute__((ext_vector_type(4)));

__device__ __forceinline__ float b2f(unsigned short u) {
    return __uint_as_float(((unsigned int)u) << 16);
}
__device__ __forceinline__ unsigned short f2b(float f) {
    unsigned int x = __float_as_uint(f);
    x += 0x7FFFu + ((x >> 16) & 1u);   // RNE
    return (unsigned short)(x >> 16);
}

// ---- x -> bf16 ----
__global__ __launch_bounds__(256) void k_xb(const float* __restrict__ x,
                                            unsigned short* __restrict__ xb) {
    int id = blockIdx.x * 256 + threadIdx.x;   // NN*32 threads exactly
    float4 v = ((const float4*)x)[id];
    ushort4 o;
    o.x = f2b(v.x); o.y = f2b(v.y); o.z = f2b(v.z); o.w = f2b(v.w);
    ((ushort4*)xb)[id] = o;
}

// ---- degree on dst ----
__global__ __launch_bounds__(256) void k_deg(const int* __restrict__ dst, int* __restrict__ deg) {
    int e = blockIdx.x * 256 + threadIdx.x;
    if (e < NE) {
        unsigned d = (unsigned)dst[e];
        if (d < NN) atomicAdd(&deg[d], 1);
    }
}

__global__ __launch_bounds__(256) void k_dinv(const int* __restrict__ deg, float* __restrict__ dinv) {
    int n = blockIdx.x * 256 + threadIdx.x;
    if (n < NN) dinv[n] = rsqrtf(fmaxf((float)deg[n] + 1.0f, 1.0f));
}

// ---- scan ----
__global__ __launch_bounds__(256) void k_scan1(const int* __restrict__ deg,
                                               int* __restrict__ row_start,
                                               int* __restrict__ part) {
    __shared__ int s[256];
    int tid = threadIdx.x;
    int i = blockIdx.x * 256 + tid;
    int v = (i < NN) ? deg[i] : 0;
    s[tid] = v;
    __syncthreads();
    for (int off = 1; off < 256; off <<= 1) {
        int t = (tid >= off) ? s[tid - off] : 0;
        __syncthreads();
        s[tid] += t;
        __syncthreads();
    }
    if (i < NN) row_start[i] = s[tid] - v;
    if (tid == 255) part[blockIdx.x] = s[255];
}

__global__ __launch_bounds__(512) void k_scan2(int* __restrict__ part) {
    __shared__ int s[512];
    int tid = threadIdx.x;
    int v = (tid < NB_SCAN) ? part[tid] : 0;
    s[tid] = v;
    __syncthreads();
    for (int off = 1; off < 512; off <<= 1) {
        int t = (tid >= off) ? s[tid - off] : 0;
        __syncthreads();
        s[tid] += t;
        __syncthreads();
    }
    if (tid < NB_SCAN) part[tid] = s[tid] - v;
}

__global__ __launch_bounds__(256) void k_scan3(int* __restrict__ row_start,
                                               const int* __restrict__ part,
                                               int* __restrict__ cursor) {
    int i = blockIdx.x * 256 + threadIdx.x;
    if (i < NN) {
        int rs = row_start[i] + part[blockIdx.x];
        row_start[i] = rs;
        cursor[i] = rs;
    }
    if (i == 0) row_start[NN] = NE;
}

// ---- CSR fill, packed 8B records ----
__global__ __launch_bounds__(256) void k_fill(const int* __restrict__ src,
                                              const int* __restrict__ dst,
                                              const float* __restrict__ dinv,
                                              int* __restrict__ cursor,
                                              int2* __restrict__ csr) {
    int e = blockIdx.x * 256 + threadIdx.x;
    if (e >= NE) return;
    unsigned s = (unsigned)src[e], d = (unsigned)dst[e];
    if (s >= NN || d >= NN) return;
    int pos = atomicAdd(&cursor[d], 1);
    csr[pos] = make_int2((int)s, __float_as_int(dinv[s] * dinv[d]));
}

// ---- layer-1 aggregate: P[n][0,256) = bf16( xb[n]*sn + sum w_e*xb[src_e] ) ----
__global__ __launch_bounds__(256) void k_agg1(const unsigned short* __restrict__ xb,
                                              const float* __restrict__ dinv,
                                              const int* __restrict__ row_start,
                                              const int2* __restrict__ csr,
                                              char* __restrict__ P) {
    int node = blockIdx.x * 4 + (threadIdx.x >> 6);   // grid = NN/4 exactly
    int lane = threadIdx.x & 63;
    float dv = dinv[node]; float sn = dv * dv;
    unsigned int sv = ((const unsigned int*)(xb + (size_t)node * 128))[lane];
    float ax = b2f((unsigned short)(sv & 0xFFFF)) * sn;
    float ay = b2f((unsigned short)(sv >> 16)) * sn;
    int base = row_start[node], end = row_start[node + 1];
    for (int i0 = base; i0 < end; i0 += 64) {
        int idx = i0 + lane;
        int2 rec = make_int2(0, 0);
        if (idx < end) rec = csr[idx];
        int m = min(64, end - i0);
        int j = 0;
        for (; j + 1 < m; j += 2) {
            int   s0 = __shfl(rec.x, j),  s1 = __shfl(rec.x, j + 1);
            float w0 = __int_as_float(__shfl(rec.y, j));
            float w1 = __int_as_float(__shfl(rec.y, j + 1));
            unsigned int v0 = ((const unsigned int*)(xb + (size_t)s0 * 128))[lane];
            unsigned int v1 = ((const unsigned int*)(xb + (size_t)s1 * 128))[lane];
            ax = fmaf(b2f((unsigned short)(v0 & 0xFFFF)), w0, ax);
            ay = fmaf(b2f((unsigned short)(v0 >> 16)),    w0, ay);
            ax = fmaf(b2f((unsigned short)(v1 & 0xFFFF)), w1, ax);
            ay = fmaf(b2f((unsigned short)(v1 >> 16)),    w1, ay);
        }
        if (j < m) {
            int s0 = __shfl(rec.x, j);
            float w0 = __int_as_float(__shfl(rec.y, j));
            unsigned int v0 = ((const unsigned int*)(xb + (size_t)s0 * 128))[lane];
            ax = fmaf(b2f((unsigned short)(v0 & 0xFFFF)), w0, ax);
            ay = fmaf(b2f((unsigned short)(v0 >> 16)),    w0, ay);
        }
    }
    unsigned int o = (unsigned int)f2b(ax) | ((unsigned int)f2b(ay) << 16);
    ((unsigned int*)(P + (size_t)node * 512))[lane] = o;
}

// ---- GEMM1 (MFMA): h2 = bf16(relu(agg @ W1 + b1)) into P[256,512) ----
// 64 rows/block, 4 waves x 16 rows; W1 LDS-swizzled for ds_read_b128 B-frags.
__global__ __launch_bounds__(256) void k_gemm1(const float* __restrict__ W1,
                                               const float* __restrict__ b1,
                                               char* __restrict__ P) {
    __shared__ short Wl[16384];        // 32 KB: [ct(8)][ks(4)][lane(64)][j(8)]
    __shared__ short Cl[4][16][128];   // 16 KB
    const int tid = threadIdx.x;
    const int w = tid >> 6, lane = tid & 63;
    const int r0 = blockIdx.x * 64;

    for (int i = tid; i < 16384; i += 256) {
        int j = i & 7, l = (i >> 3) & 63, ks = (i >> 9) & 3, ct = i >> 11;
        int k = ks * 32 + ((l >> 4) << 3) + j;
        int c = ct * 16 + (l & 15);
        Wl[i] = (short)f2b(W1[k * 128 + c]);
    }
    __syncthreads();

    const int m = r0 + w * 16 + (lane & 15);
    const int quad = lane >> 4;
    const bool mok = (m < NN);
    bf16x8 a[4];
#pragma unroll
    for (int ks = 0; ks < 4; ++ks) {
        if (mok) a[ks] = *(const bf16x8*)(P + (size_t)m * 512 + (ks * 32 + quad * 8) * 2);
        else     a[ks] = bf16x8{0,0,0,0,0,0,0,0};
    }
#pragma unroll
    for (int ct = 0; ct < 8; ++ct) {
        f32x4 c = {0.f, 0.f, 0.f, 0.f};
#pragma unroll
        for (int ks = 0; ks < 4; ++ks) {
            bf16x8 b = *(const bf16x8*)&Wl[((ct * 4 + ks) * 64 + lane) * 8];
            c = __builtin_amdgcn_mfma_f32_16x16x32_bf16(a[ks], b, c, 0, 0, 0);
        }
        int col = ct * 16 + (lane & 15);
        float bias = b1[col];
#pragma unroll
        for (int r = 0; r < 4; ++r)
            Cl[w][quad * 4 + r][col] = (short)f2b(fmaxf(c[r] + bias, 0.f));
    }
    // write 16 rows x 256 B (bf16 h2) coalesced
    for (int row = 0; row < 16; ++row) {
        int node = r0 + w * 16 + row;
        if (node < NN)
            *(unsigned int*)(P + (size_t)node * 512 + 256 + lane * 4) =
                ((const unsigned int*)&Cl[w][row][0])[lane];
    }
}

// ---- GEMM2 (MFMA): t2 = bf16(h2 @ W2) into P[0,128) ----
__global__ __launch_bounds__(256) void k_gemm2(const float* __restrict__ W2,
                                               char* __restrict__ P) {
    __shared__ short Wl[8192];         // 16 KB: [ct(4)][ks(4)][lane(64)][j(8)]
    __shared__ short Cl[4][16][64];    // 8 KB
    const int tid = threadIdx.x;
    const int w = tid >> 6, lane = tid & 63;
    const int r0 = blockIdx.x * 64;

    for (int i = tid; i < 8192; i += 256) {
        int j = i & 7, l = (i >> 3) & 63, ks = (i >> 9) & 3, ct = i >> 11;
        int k = ks * 32 + ((l >> 4) << 3) + j;
        int c = ct * 16 + (l & 15);
        Wl[i] = (short)f2b(W2[k * 64 + c]);
    }
    __syncthreads();

    const int m = r0 + w * 16 + (lane & 15);
    const int quad = lane >> 4;
    const bool mok = (m < NN);
    bf16x8 a[4];
#pragma unroll
    for (int ks = 0; ks < 4; ++ks) {
        if (mok) a[ks] = *(const bf16x8*)(P + (size_t)m * 512 + 256 + (ks * 32 + quad * 8) * 2);
        else     a[ks] = bf16x8{0,0,0,0,0,0,0,0};
    }
#pragma unroll
    for (int ct = 0; ct < 4; ++ct) {
        f32x4 c = {0.f, 0.f, 0.f, 0.f};
#pragma unroll
        for (int ks = 0; ks < 4; ++ks) {
            bf16x8 b = *(const bf16x8*)&Wl[((ct * 4 + ks) * 64 + lane) * 8];
            c = __builtin_amdgcn_mfma_f32_16x16x32_bf16(a[ks], b, c, 0, 0, 0);
        }
        int col = ct * 16 + (lane & 15);
#pragma unroll
        for (int r = 0; r < 4; ++r)
            Cl[w][quad * 4 + r][col] = (short)f2b(c[r]);
    }
    // write 16 rows x 128 B: 2 rows per iter (32 lanes each)
    for (int it = 0; it < 8; ++it) {
        int row = it * 2 + (lane >> 5), u = lane & 31;
        int node = r0 + w * 16 + row;
        if (node < NN)
            *(unsigned int*)(P + (size_t)node * 512 + u * 4) =
                ((const unsigned int*)&Cl[w][row][0])[u];
    }
}

// ---- layer-2 aggregate + epilogue: out = t2*sn + sum w_e*t2[src] + b2 ----
__global__ __launch_bounds__(256) void k_agg2(const float* __restrict__ dinv,
                                              const int* __restrict__ row_start,
                                              const int2* __restrict__ csr,
                                              const char* __restrict__ P,
                                              const float* __restrict__ b2,
                                              float* __restrict__ outp) {
    int node = blockIdx.x * 4 + (threadIdx.x >> 6);   // grid = NN/4 exactly
    int lane = threadIdx.x & 63;
    float dv = dinv[node]; float sn = dv * dv;
    float acc = b2f(*(const unsigned short*)(P + (size_t)node * 512 + lane * 2)) * sn;
    int base = row_start[node], end = row_start[node + 1];
    for (int i0 = base; i0 < end; i0 += 64) {
        int idx = i0 + lane;
        int2 rec = make_int2(0, 0);
        if (idx < end) rec = csr[idx];
        int m = min(64, end - i0);
        int j = 0;
        for (; j + 1 < m; j += 2) {
            int   s0 = __shfl(rec.x, j),  s1 = __shfl(rec.x, j + 1);
            float w0 = __int_as_float(__shfl(rec.y, j));
            float w1 = __int_as_float(__shfl(rec.y, j + 1));
            float v0 = b2f(*(const unsigned short*)(P + (size_t)s0 * 512 + lane * 2));
            float v1 = b2f(*(const unsigned short*)(P + (size_t)s1 * 512 + lane * 2));
            acc = fmaf(v0, w0, acc);
            acc = fmaf(v1, w1, acc);
        }
        if (j < m) {
            int s0 = __shfl(rec.x, j);
            float w0 = __int_as_float(__shfl(rec.y, j));
            float v0 = b2f(*(const unsigned short*)(P + (size_t)s0 * 512 + lane * 2));
            acc = fmaf(v0, w0, acc);
        }
    }
    outp[(size_t)node * 64 + lane] = acc + b2[lane];
}

extern "C" void kernel_launch(void* const* d_in, const int* in_sizes, int n_in,
                              void* d_out, int out_size, void* d_ws, size_t ws_size,
                              hipStream_t stream) {
    const float* x  = (const float*)d_in[0];
    const int*   ei = (const int*)d_in[1];
    const float* W1 = (const float*)d_in[2];
    const float* b1 = (const float*)d_in[3];
    const float* W2 = (const float*)d_in[4];
    const float* b2 = (const float*)d_in[5];
    float* out = (float*)d_out;
    const int* src = ei;
    const int* dst = ei + NE;

    char* ws = (char*)d_ws;
    int*            deg       = (int*)(ws + 0);
    float*          dinv      = (float*)(ws + 400000);
    int*            row_start = (int*)(ws + 800000);
    int*            cursor    = (int*)(ws + 1200016);
    int*            part      = (int*)(ws + 1600016);
    unsigned short* xb        = (unsigned short*)(ws + 1601600);
    int2*           csr       = (int2*)(ws + 27201600);
    char*           P         = ws + 40001600;

    hipMemsetAsync(deg, 0, (size_t)NN * 4, stream);

    k_xb   <<<NN / 8, 256, 0, stream>>>(x, xb);
    k_deg  <<<NE / 256, 256, 0, stream>>>(dst, deg);
    k_dinv <<<NB_SCAN, 256, 0, stream>>>(deg, dinv);
    k_scan1<<<NB_SCAN, 256, 0, stream>>>(deg, row_start, part);
    k_scan2<<<1, 512, 0, stream>>>(part);
    k_scan3<<<NB_SCAN, 256, 0, stream>>>(row_start, part, cursor);
    k_fill <<<NE / 256, 256, 0, stream>>>(src, dst, dinv, cursor, csr);

    k_agg1 <<<NN / 4, 256, 0, stream>>>(xb, dinv, row_start, csr, P);
    k_gemm1<<<NBG, 256, 0, stream>>>(W1, b1, P);
    k_gemm2<<<NBG, 256, 0, stream>>>(W2, P);
    k_agg2 <<<NN / 4, 256, 0, stream>>>(dinv, row_start, csr, P, b2, out);
}